// Round 6
// baseline (202.198 us; speedup 1.0000x reference)
//
#include <hip/hip_runtime.h>
#include <stdint.h>
#include <stddef.h>

// CliffordLinear as one bf16 GEMM:
//   out[b, o*8+l] = sum_{i,k} X[b, i*8+k] * Wt[o*8+l, i*8+k] + bias[o*8+l]
//   Wt[(o,l),(i,k)] = sum_j cayley[j,k,l] * W[o,i,j]
// M=8192, N=2048, K=2048. bf16 MFMA, fp32 accumulate.
//
// R6: R5 pipeline (static-dbuf, single barrier/iter, source-side XOR swizzle
// = 0 bank conflicts, XCD band swizzle) with the MFMA swapped to
// 32x32x16_bf16: 17% less matrix-pipe time (m06: 2382 vs 2075 TF) and half
// the MFMA instruction count at identical LDS traffic. Wave's 64x64 region =
// 2x2 grid of 32x32 tiles, 2 k-slices of 16 per BK=32 iteration.
// Also: cast + fold merged into one prep dispatch (one fewer launch gap).

typedef __bf16 bf16x8  __attribute__((ext_vector_type(8)));
typedef float  f32x4   __attribute__((ext_vector_type(4)));
typedef float  f32x16  __attribute__((ext_vector_type(16)));

#define BM 128
#define BN 128
#define BK 32

__device__ __forceinline__ void async_copy16(void* lds_dst, const void* g_src) {
    // global -> LDS direct copy, 16B/lane; dest is wave-uniform base, HW
    // scatters lane i to base + i*16.
    __builtin_amdgcn_global_load_lds(
        (__attribute__((address_space(1))) void*)g_src,
        (__attribute__((address_space(3))) void*)lds_dst,
        16, 0, 0);
}

// ---------------- kernel 1: fused prep (cast X -> bf16, fold Cayley) -------
// blocks [0, castBlocks): cast; blocks [castBlocks, ...): fold.
__global__ __launch_bounds__(256) void prep_kernel(
    const float* __restrict__ x, __bf16* __restrict__ Xb, long nx,
    const float* __restrict__ W, const float* __restrict__ cayley,
    __bf16* __restrict__ Wt, int Cin, int Cout, int castBlocks)
{
    __shared__ float Cay[512];
    if ((int)blockIdx.x < castBlocks) {
        long i = ((long)blockIdx.x * 256 + threadIdx.x) * 8;
        if (i + 8 <= nx) {
            const f32x4* p = (const f32x4*)(x + i);
            f32x4 v0 = p[0];
            f32x4 v1 = p[1];
            bf16x8 o;
            o[0] = (__bf16)v0[0]; o[1] = (__bf16)v0[1];
            o[2] = (__bf16)v0[2]; o[3] = (__bf16)v0[3];
            o[4] = (__bf16)v1[0]; o[5] = (__bf16)v1[1];
            o[6] = (__bf16)v1[2]; o[7] = (__bf16)v1[3];
            *(bf16x8*)(Xb + i) = o;
        }
        return;
    }
    // ---- fold: Wt[n][i*8+k] = sum_j C[j,k,l] * W[o,i,j], n = o*8+l
    for (int t = threadIdx.x; t < 512; t += 256) Cay[t] = cayley[t];
    __syncthreads();

    int flat = (blockIdx.x - castBlocks) * 256 + threadIdx.x;  // n*Cin + i
    int total = Cout * 8 * Cin;
    if (flat >= total) return;
    int i = flat % Cin;
    int n = flat / Cin;
    int o = n >> 3, l = n & 7;

    const float* wrow = W + ((size_t)o * Cin + i) * 8;
    float w8[8];
    #pragma unroll
    for (int j = 0; j < 8; ++j) w8[j] = wrow[j];

    bf16x8 outv;
    #pragma unroll
    for (int k = 0; k < 8; ++k) {
        float s = 0.f;
        #pragma unroll
        for (int j = 0; j < 8; ++j) s += Cay[j * 64 + k * 8 + l] * w8[j];
        outv[k] = (__bf16)s;
    }
    *(bf16x8*)(Wt + (size_t)n * (Cin * 8) + i * 8) = outv;
}

// ---------------- kernel 2: bf16 GEMM, C = A * Bt^T + bias ----------------
// A  : [M][K] bf16 (row-major, pre-cast)
// Bt : [N][K] bf16 (row-major)
// C  : [M][N] fp32
//
// LDS layout (per buffer): tile row = 32 bf16 = 4 groups of 8 bf16 (16 B).
// Physical group p of row r holds GLOBAL group p ^ ((r>>1) & 3) (swizzle on
// the staging SOURCE address; global_load_lds lane scatter untouched).
//
// 32x32x16 fragment mapping (standard CDNA extension of the verified 16x16
// maps): A[m = lane&31][k = (lane>>5)*8 + j]; B[n = lane&31][k likewise];
// C/D col = lane&31, row = (reg&3) + 8*(reg>>2) + 4*(lane>>5)  [m74/m101].
// Frag read: row = w? + tile*32 + l32 (swizzle key (l32>>1)&3, invariant
// under +32/+64 row offsets), group = kslice*2 + (lane>>5).
// Bank check per 16-lane b128 phase: even rows -> banks 0-15, odd -> 16-31;
// 4 swizzle keys x 2 lanes per group = 2-way aliasing = free (R3/R4: 0).
__global__ __launch_bounds__(256) void gemm_bt_kernel(
    const __bf16* __restrict__ A,
    const __bf16* __restrict__ Bt,
    const float*  __restrict__ bias,
    float* __restrict__ C,
    int M, int N, int K)
{
    __shared__ __align__(16) __bf16 As0[BM * BK];  // 8 KB each
    __shared__ __align__(16) __bf16 As1[BM * BK];
    __shared__ __align__(16) __bf16 Bs0[BN * BK];
    __shared__ __align__(16) __bf16 Bs1[BN * BK];

    const int tid  = threadIdx.x;
    const int wave = tid >> 6;
    const int lane = tid & 63;
    const int l32  = lane & 31;
    const int half = lane >> 5;   // 0..1

    // --- XCD band swizzle: all 16 N-blocks of an M-band share bid%8 -> one XCD
    const int bid   = blockIdx.x;                    // 0..1023
    const int band  = (bid & 7) | ((bid >> 7) << 3); // 0..63
    const int ncol  = (bid >> 3) & 15;               // 0..15
    const int mBase = band * BM;
    const int nBase = ncol * BN;

    // --- staging: 1 KB chunk = 16 rows of 64 B; 8 chunks per buffer for A/B;
    // wave w loads chunks 2w, 2w+1 of both. XOR swizzle on source group.
    const int srow = lane >> 2;                        // 0..15 row in chunk
    const int sgrp = (lane & 3) ^ ((srow >> 1) & 3);   // swizzled 16B-group

    const __bf16* gA0 = A  + (size_t)(mBase + (2 * wave + 0) * 16 + srow) * K + sgrp * 8;
    const __bf16* gA1 = A  + (size_t)(mBase + (2 * wave + 1) * 16 + srow) * K + sgrp * 8;
    const __bf16* gB0 = Bt + (size_t)(nBase + (2 * wave + 0) * 16 + srow) * K + sgrp * 8;
    const __bf16* gB1 = Bt + (size_t)(nBase + (2 * wave + 1) * 16 + srow) * K + sgrp * 8;
    const int cOff0 = (2 * wave + 0) * 512;   // 512 bf16 = 1 KB chunk
    const int cOff1 = (2 * wave + 1) * 512;

    // --- compute: wave quadrant 64x64 = 2x2 of 32x32 MFMA tiles
    const int wm = (wave >> 1) * 64;
    const int wn = (wave & 1) * 64;
    const int key = (l32 >> 1) & 3;
    const int g0  = ((0 + half) ^ key) * 8;   // k-slice 0 (k 0..15)
    const int g1  = ((2 + half) ^ key) * 8;   // k-slice 1 (k 16..31)
    const int rA  = (wm + l32) * BK;          // +32*BK for mt=1
    const int rB  = (wn + l32) * BK;

    f32x16 acc[2][2] = {};

#define PREFETCH(BUFA, BUFB, KOFF)                       \
    do {                                                 \
        async_copy16(&BUFA[cOff0], gA0 + (KOFF));        \
        async_copy16(&BUFA[cOff1], gA1 + (KOFF));        \
        async_copy16(&BUFB[cOff0], gB0 + (KOFF));        \
        async_copy16(&BUFB[cOff1], gB1 + (KOFF));        \
    } while (0)

#define COMPUTE(BUFA, BUFB)                                                \
    do {                                                                   \
        bf16x8 a00 = *(const bf16x8*)(&BUFA[rA] + g0);                     \
        bf16x8 a10 = *(const bf16x8*)(&BUFA[rA + 32 * BK] + g0);           \
        bf16x8 b00 = *(const bf16x8*)(&BUFB[rB] + g0);                     \
        bf16x8 b10 = *(const bf16x8*)(&BUFB[rB + 32 * BK] + g0);           \
        bf16x8 a01 = *(const bf16x8*)(&BUFA[rA] + g1);                     \
        bf16x8 a11 = *(const bf16x8*)(&BUFA[rA + 32 * BK] + g1);           \
        bf16x8 b01 = *(const bf16x8*)(&BUFB[rB] + g1);                     \
        bf16x8 b11 = *(const bf16x8*)(&BUFB[rB + 32 * BK] + g1);           \
        acc[0][0] = __builtin_amdgcn_mfma_f32_32x32x16_bf16(a00, b00, acc[0][0], 0, 0, 0); \
        acc[0][1] = __builtin_amdgcn_mfma_f32_32x32x16_bf16(a00, b10, acc[0][1], 0, 0, 0); \
        acc[1][0] = __builtin_amdgcn_mfma_f32_32x32x16_bf16(a10, b00, acc[1][0], 0, 0, 0); \
        acc[1][1] = __builtin_amdgcn_mfma_f32_32x32x16_bf16(a10, b10, acc[1][1], 0, 0, 0); \
        acc[0][0] = __builtin_amdgcn_mfma_f32_32x32x16_bf16(a01, b01, acc[0][0], 0, 0, 0); \
        acc[0][1] = __builtin_amdgcn_mfma_f32_32x32x16_bf16(a01, b11, acc[0][1], 0, 0, 0); \
        acc[1][0] = __builtin_amdgcn_mfma_f32_32x32x16_bf16(a11, b01, acc[1][0], 0, 0, 0); \
        acc[1][1] = __builtin_amdgcn_mfma_f32_32x32x16_bf16(a11, b11, acc[1][1], 0, 0, 0); \
    } while (0)

    // --- prologue: stage k=0 into buffer 0
    PREFETCH(As0, Bs0, 0);

    // --- main loop: phase = barrier, prefetch other buffer, compute this one.
    // Barrier-top vmcnt(0) drain covers loads issued one compute phase ago.
    int k0 = 0;
    for (; k0 < K - 2 * BK; k0 += 2 * BK) {
        __syncthreads();
        PREFETCH(As1, Bs1, k0 + BK);
        COMPUTE(As0, Bs0);

        __syncthreads();
        PREFETCH(As0, Bs0, k0 + 2 * BK);
        COMPUTE(As1, Bs1);
    }

    // --- tail pair
    __syncthreads();
    PREFETCH(As1, Bs1, k0 + BK);
    COMPUTE(As0, Bs0);

    __syncthreads();
    COMPUTE(As1, Bs1);

#undef PREFETCH
#undef COMPUTE

    // --- epilogue: C/D col = lane&31, row = (reg&3) + 8*(reg>>2) + 4*half
    #pragma unroll
    for (int nt = 0; nt < 2; ++nt) {
        const int col = nBase + wn + nt * 32 + l32;
        const float bv = bias[col];
        #pragma unroll
        for (int mt = 0; mt < 2; ++mt) {
            const int rowBase = mBase + wm + mt * 32 + 4 * half;
            #pragma unroll
            for (int r = 0; r < 16; ++r) {
                const int row = rowBase + (r & 3) + 8 * (r >> 2);
                C[(size_t)row * N + col] = acc[mt][nt][r] + bv;
            }
        }
    }
}

extern "C" void kernel_launch(void* const* d_in, const int* in_sizes, int n_in,
                              void* d_out, int out_size, void* d_ws, size_t ws_size,
                              hipStream_t stream) {
    const float* x      = (const float*)d_in[0];  // [B][Cin][8]
    const float* weight = (const float*)d_in[1];  // [Cout][Cin][8]
    const float* bias   = (const float*)d_in[2];  // [Cout][8]
    const float* cayley = (const float*)d_in[3];  // [8][8][8]
    float* out = (float*)d_out;                   // [B][Cout][8]

    const int Cout = in_sizes[2] / 8;
    const int Cin  = in_sizes[1] / (Cout * 8);
    const int Bm   = in_sizes[0] / (Cin * 8);
    const int M = Bm;          // 8192
    const int N = Cout * 8;    // 2048
    const int K = Cin * 8;     // 2048

    __bf16* Xb = (__bf16*)d_ws;                               // M*K bf16 = 32 MB
    __bf16* Wt = (__bf16*)((char*)d_ws + (size_t)M * K * 2);  // N*K bf16 = 8 MB

    // 1) fused prep: cast X + fold Cayley into Wt, one dispatch
    long nx = (long)M * K;
    int castBlocks = (int)(nx / 8 / 256);               // nx divisible by 2048
    int foldBlocks = (N * Cin + 255) / 256;
    prep_kernel<<<castBlocks + foldBlocks, 256, 0, stream>>>(
        x, Xb, nx, weight, cayley, Wt, Cin, Cout, castBlocks);

    // 2) GEMM
    int grid = (M / BM) * (N / BN);   // 64 * 16 = 1024
    gemm_bt_kernel<<<grid, 256, 0, stream>>>(Xb, Wt, bias, out, M, N, K);
}

// Round 7
// 188.732 us; speedup vs baseline: 1.0713x; 1.0713x over previous
//
#include <hip/hip_runtime.h>
#include <stdint.h>
#include <stddef.h>

// CliffordLinear as one bf16 GEMM:
//   out[b, o*8+l] = sum_{i,k} X[b, i*8+k] * Wt[o*8+l, i*8+k] + bias[o*8+l]
//   Wt[(o,l),(i,k)] = sum_j cayley[j,k,l] * W[o,i,j]
// M=8192, N=2048, K=2048. bf16 MFMA, fp32 accumulate.
//
// R7: revert to the R5 GEMM body (16x16x32 MFMA, quad fragment pattern --
// verified SQ_LDS_BANK_CONFLICT = 0; R6's 32x32 pattern conflicted under the
// HW's interleaved half-wave LDS phasing) + __launch_bounds__(256, 4):
// cap unified regs at 128 (64 arch + 64 acc) so all 4 blocks/CU are
// co-resident (R5: 76+64 = 140 -> 3 waves/SIMD -> 3 blocks resident, 4th
// block ran as a ~1/3-occupancy tail). Fused prep kernel kept from R6.

typedef __bf16 bf16x8  __attribute__((ext_vector_type(8)));
typedef float  f32x4   __attribute__((ext_vector_type(4)));

#define BM 128
#define BN 128
#define BK 32

__device__ __forceinline__ void async_copy16(void* lds_dst, const void* g_src) {
    // global -> LDS direct copy, 16B/lane; dest is wave-uniform base, HW
    // scatters lane i to base + i*16.
    __builtin_amdgcn_global_load_lds(
        (__attribute__((address_space(1))) void*)g_src,
        (__attribute__((address_space(3))) void*)lds_dst,
        16, 0, 0);
}

// ---------------- kernel 1: fused prep (cast X -> bf16, fold Cayley) -------
// blocks [0, castBlocks): cast; blocks [castBlocks, ...): fold.
__global__ __launch_bounds__(256) void prep_kernel(
    const float* __restrict__ x, __bf16* __restrict__ Xb, long nx,
    const float* __restrict__ W, const float* __restrict__ cayley,
    __bf16* __restrict__ Wt, int Cin, int Cout, int castBlocks)
{
    __shared__ float Cay[512];
    if ((int)blockIdx.x < castBlocks) {
        long i = ((long)blockIdx.x * 256 + threadIdx.x) * 8;
        if (i + 8 <= nx) {
            const f32x4* p = (const f32x4*)(x + i);
            f32x4 v0 = p[0];
            f32x4 v1 = p[1];
            bf16x8 o;
            o[0] = (__bf16)v0[0]; o[1] = (__bf16)v0[1];
            o[2] = (__bf16)v0[2]; o[3] = (__bf16)v0[3];
            o[4] = (__bf16)v1[0]; o[5] = (__bf16)v1[1];
            o[6] = (__bf16)v1[2]; o[7] = (__bf16)v1[3];
            *(bf16x8*)(Xb + i) = o;
        }
        return;
    }
    // ---- fold: Wt[n][i*8+k] = sum_j C[j,k,l] * W[o,i,j], n = o*8+l
    for (int t = threadIdx.x; t < 512; t += 256) Cay[t] = cayley[t];
    __syncthreads();

    int flat = (blockIdx.x - castBlocks) * 256 + threadIdx.x;  // n*Cin + i
    int total = Cout * 8 * Cin;
    if (flat >= total) return;
    int i = flat % Cin;
    int n = flat / Cin;
    int o = n >> 3, l = n & 7;

    const float* wrow = W + ((size_t)o * Cin + i) * 8;
    float w8[8];
    #pragma unroll
    for (int j = 0; j < 8; ++j) w8[j] = wrow[j];

    bf16x8 outv;
    #pragma unroll
    for (int k = 0; k < 8; ++k) {
        float s = 0.f;
        #pragma unroll
        for (int j = 0; j < 8; ++j) s += Cay[j * 64 + k * 8 + l] * w8[j];
        outv[k] = (__bf16)s;
    }
    *(bf16x8*)(Wt + (size_t)n * (Cin * 8) + i * 8) = outv;
}

// ---------------- kernel 2: bf16 GEMM, C = A * Bt^T + bias ----------------
// A  : [M][K] bf16 (row-major, pre-cast)
// Bt : [N][K] bf16 (row-major)
// C  : [M][N] fp32
//
// LDS layout (per buffer): tile row = 32 bf16 = 4 groups of 8 bf16 (16 B).
// Physical group p of row r holds GLOBAL group p ^ ((r>>1) & 3) (swizzle on
// the staging SOURCE address; global_load_lds lane scatter untouched).
// Fragment read: physical offset (quad ^ ((l16>>1) & 3)) * 8. R4/R5 measured
// SQ_LDS_BANK_CONFLICT = 0 with this pattern (disjoint bank quads even under
// interleaved half-wave phasing -- R6's 32x32 pattern was not, 4 cyc/read).
__global__ __launch_bounds__(256, 4) void gemm_bt_kernel(
    const __bf16* __restrict__ A,
    const __bf16* __restrict__ Bt,
    const float*  __restrict__ bias,
    float* __restrict__ C,
    int M, int N, int K)
{
    __shared__ __align__(16) __bf16 As0[BM * BK];  // 8 KB each
    __shared__ __align__(16) __bf16 As1[BM * BK];
    __shared__ __align__(16) __bf16 Bs0[BN * BK];
    __shared__ __align__(16) __bf16 Bs1[BN * BK];

    const int tid  = threadIdx.x;
    const int wave = tid >> 6;
    const int lane = tid & 63;
    const int quad = lane >> 4;   // 0..3
    const int l16  = lane & 15;   // 0..15

    // --- XCD band swizzle: all 16 N-blocks of an M-band share bid%8 -> one XCD
    const int bid   = blockIdx.x;                    // 0..1023
    const int band  = (bid & 7) | ((bid >> 7) << 3); // 0..63
    const int ncol  = (bid >> 3) & 15;               // 0..15
    const int mBase = band * BM;
    const int nBase = ncol * BN;

    // --- staging: 1 KB chunk = 16 rows of 64 B; 8 chunks per buffer for A/B;
    // wave w loads chunks 2w, 2w+1 of both. XOR swizzle on source group.
    const int srow = lane >> 2;                        // 0..15 row in chunk
    const int sgrp = (lane & 3) ^ ((srow >> 1) & 3);   // swizzled 16B-group

    const __bf16* gA0 = A  + (size_t)(mBase + (2 * wave + 0) * 16 + srow) * K + sgrp * 8;
    const __bf16* gA1 = A  + (size_t)(mBase + (2 * wave + 1) * 16 + srow) * K + sgrp * 8;
    const __bf16* gB0 = Bt + (size_t)(nBase + (2 * wave + 0) * 16 + srow) * K + sgrp * 8;
    const __bf16* gB1 = Bt + (size_t)(nBase + (2 * wave + 1) * 16 + srow) * K + sgrp * 8;
    const int cOff0 = (2 * wave + 0) * 512;   // 512 bf16 = 1 KB chunk
    const int cOff1 = (2 * wave + 1) * 512;

    // --- compute: wave quadrant (64x64), 4x4 grid of 16x16x32 MFMA tiles
    const int wm = (wave >> 1) * 64;
    const int wn = (wave & 1) * 64;
    const int offq = (quad ^ ((l16 >> 1) & 3)) * 8;  // swizzled frag offset
    const int rowA = (wm + l16) * BK;
    const int rowB = (wn + l16) * BK;

    f32x4 acc[4][4] = {};

#define PREFETCH(BUFA, BUFB, KOFF)                       \
    do {                                                 \
        async_copy16(&BUFA[cOff0], gA0 + (KOFF));        \
        async_copy16(&BUFA[cOff1], gA1 + (KOFF));        \
        async_copy16(&BUFB[cOff0], gB0 + (KOFF));        \
        async_copy16(&BUFB[cOff1], gB1 + (KOFF));        \
    } while (0)

#define COMPUTE(BUFA, BUFB)                                               \
    do {                                                                  \
        const __bf16* fA = &BUFA[rowA] + offq;                            \
        const __bf16* fB = &BUFB[rowB] + offq;                            \
        bf16x8 af[4], bfr[4];                                             \
        _Pragma("unroll")                                                 \
        for (int mt = 0; mt < 4; ++mt)                                    \
            af[mt] = *(const bf16x8*)(fA + mt * 16 * BK);                 \
        _Pragma("unroll")                                                 \
        for (int nt = 0; nt < 4; ++nt)                                    \
            bfr[nt] = *(const bf16x8*)(fB + nt * 16 * BK);                \
        _Pragma("unroll")                                                 \
        for (int mt = 0; mt < 4; ++mt)                                    \
            _Pragma("unroll")                                             \
            for (int nt = 0; nt < 4; ++nt)                                \
                acc[mt][nt] = __builtin_amdgcn_mfma_f32_16x16x32_bf16(    \
                    af[mt], bfr[nt], acc[mt][nt], 0, 0, 0);               \
    } while (0)

    // --- prologue: stage k=0 into buffer 0
    PREFETCH(As0, Bs0, 0);

    // --- main loop: phase = barrier, prefetch other buffer, compute this one.
    // Barrier-top vmcnt(0) drain covers loads issued one compute phase ago.
    int k0 = 0;
    for (; k0 < K - 2 * BK; k0 += 2 * BK) {
        __syncthreads();
        PREFETCH(As1, Bs1, k0 + BK);
        COMPUTE(As0, Bs0);

        __syncthreads();
        PREFETCH(As0, Bs0, k0 + 2 * BK);
        COMPUTE(As1, Bs1);
    }

    // --- tail pair
    __syncthreads();
    PREFETCH(As1, Bs1, k0 + BK);
    COMPUTE(As0, Bs0);

    __syncthreads();
    COMPUTE(As1, Bs1);

#undef PREFETCH
#undef COMPUTE

    // --- epilogue: C/D layout col = lane&15, row = quad*4 + reg
    float bv[4];
    #pragma unroll
    for (int nt = 0; nt < 4; ++nt)
        bv[nt] = bias[nBase + wn + nt * 16 + l16];

    #pragma unroll
    for (int mt = 0; mt < 4; ++mt) {
        #pragma unroll
        for (int nt = 0; nt < 4; ++nt) {
            const int col = nBase + wn + nt * 16 + l16;
            #pragma unroll
            for (int r = 0; r < 4; ++r) {
                const int row = mBase + wm + mt * 16 + quad * 4 + r;
                C[(size_t)row * N + col] = acc[mt][nt][r] + bv[nt];
            }
        }
    }
}

extern "C" void kernel_launch(void* const* d_in, const int* in_sizes, int n_in,
                              void* d_out, int out_size, void* d_ws, size_t ws_size,
                              hipStream_t stream) {
    const float* x      = (const float*)d_in[0];  // [B][Cin][8]
    const float* weight = (const float*)d_in[1];  // [Cout][Cin][8]
    const float* bias   = (const float*)d_in[2];  // [Cout][8]
    const float* cayley = (const float*)d_in[3];  // [8][8][8]
    float* out = (float*)d_out;                   // [B][Cout][8]

    const int Cout = in_sizes[2] / 8;
    const int Cin  = in_sizes[1] / (Cout * 8);
    const int Bm   = in_sizes[0] / (Cin * 8);
    const int M = Bm;          // 8192
    const int N = Cout * 8;    // 2048
    const int K = Cin * 8;     // 2048

    __bf16* Xb = (__bf16*)d_ws;                               // M*K bf16 = 32 MB
    __bf16* Wt = (__bf16*)((char*)d_ws + (size_t)M * K * 2);  // N*K bf16 = 8 MB

    // 1) fused prep: cast X + fold Cayley into Wt, one dispatch
    long nx = (long)M * K;
    int castBlocks = (int)(nx / 8 / 256);               // nx divisible by 2048
    int foldBlocks = (N * Cin + 255) / 256;
    prep_kernel<<<castBlocks + foldBlocks, 256, 0, stream>>>(
        x, Xb, nx, weight, cayley, Wt, Cin, Cout, castBlocks);

    // 2) GEMM
    int grid = (M / BM) * (N / BN);   // 64 * 16 = 1024
    gemm_bt_kernel<<<grid, 256, 0, stream>>>(Xb, Wt, bias, out, M, N, K);
}